// Round 1
// baseline (280.145 us; speedup 1.0000x reference)
//
#include <hip/hip_runtime.h>
#include <hip/hip_bf16.h>

typedef __attribute__((ext_vector_type(4))) float f32x4;
typedef __attribute__((ext_vector_type(8))) short s16x8;
typedef __attribute__((ext_vector_type(4))) short s16x4;
typedef __attribute__((ext_vector_type(4))) int   i32x4;

static __device__ __forceinline__ unsigned short f2bf_bits(float f) {
    unsigned u = __builtin_bit_cast(unsigned, f);
    u += 0x7fffu + ((u >> 16) & 1u);   // RNE; no NaNs in this problem
    return (unsigned short)(u >> 16);
}
static __device__ __forceinline__ short f2bf(float f) { return (short)f2bf_bits(f); }
static __device__ __forceinline__ unsigned pack2(float a, float b) {
    return (unsigned)f2bf_bits(a) | ((unsigned)f2bf_bits(b) << 16);
}

// ---------------- Kernel 1: QKV projection (bf16 MFMA, f32 inputs) ----------
// X [32768,1024] f32; W [64,1024] f32 (NT gemm). Outputs bf16:
//   q [B,T,64] (scaled by 0.125), k [B,T,64], vT [B,64,T].
__global__ __launch_bounds__(256) void qkv_gemm(
    const float* __restrict__ X, const float* __restrict__ Wq,
    const float* __restrict__ Wk, const float* __restrict__ Wv,
    short* __restrict__ qb, short* __restrict__ kb, short* __restrict__ vtb)
{
    const int wsel = blockIdx.x;            // 0=q, 1=k, 2=v
    const int m0 = blockIdx.y * 128;
    const float* __restrict__ W = (wsel == 0) ? Wq : ((wsel == 1) ? Wk : Wv);

    __shared__ short al[128][72];           // +8 pad: conflict-free b128 reads
    __shared__ short bl[64][72];

    const int tid = threadIdx.x;
    const int lane = tid & 63;
    const int wid = tid >> 6;
    const int wm = (wid >> 1) << 6;         // 0 / 64
    const int wn = (wid & 1) << 5;          // 0 / 32
    const int g = lane >> 4;
    const int c = lane & 15;

    f32x4 acc[4][2];
    #pragma unroll
    for (int i = 0; i < 4; ++i)
        #pragma unroll
        for (int j = 0; j < 2; ++j) acc[i][j] = (f32x4)0.0f;

    for (int kt = 0; kt < 1024; kt += 64) {
        #pragma unroll
        for (int it = 0; it < 8; ++it) {    // A-tile 128x64
            int idx = it * 256 + tid;
            int row = idx >> 4;
            int c4 = (idx & 15) << 2;
            float4 xv = *reinterpret_cast<const float4*>(X + (size_t)(m0 + row) * 1024 + kt + c4);
            s16x4 sv = { f2bf(xv.x), f2bf(xv.y), f2bf(xv.z), f2bf(xv.w) };
            *reinterpret_cast<s16x4*>(&al[row][c4]) = sv;
        }
        #pragma unroll
        for (int it = 0; it < 4; ++it) {    // B-tile 64x64
            int idx = it * 256 + tid;
            int row = idx >> 4;
            int c4 = (idx & 15) << 2;
            float4 wv = *reinterpret_cast<const float4*>(W + (size_t)row * 1024 + kt + c4);
            s16x4 sv = { f2bf(wv.x), f2bf(wv.y), f2bf(wv.z), f2bf(wv.w) };
            *reinterpret_cast<s16x4*>(&bl[row][c4]) = sv;
        }
        __syncthreads();

        s16x8 af[4][2], bfm[2][2];
        #pragma unroll
        for (int mf = 0; mf < 4; ++mf)
            #pragma unroll
            for (int kk = 0; kk < 2; ++kk)
                af[mf][kk] = *reinterpret_cast<const s16x8*>(&al[wm + mf*16 + c][kk*32 + g*8]);
        #pragma unroll
        for (int nf = 0; nf < 2; ++nf)
            #pragma unroll
            for (int kk = 0; kk < 2; ++kk)
                bfm[nf][kk] = *reinterpret_cast<const s16x8*>(&bl[wn + nf*16 + c][kk*32 + g*8]);
        #pragma unroll
        for (int kk = 0; kk < 2; ++kk)
            #pragma unroll
            for (int mf = 0; mf < 4; ++mf)
                #pragma unroll
                for (int nf = 0; nf < 2; ++nf)
                    acc[mf][nf] = __builtin_amdgcn_mfma_f32_16x16x32_bf16(af[mf][kk], bfm[nf][kk], acc[mf][nf], 0, 0, 0);
        __syncthreads();
    }

    // C/D layout: col = lane&15, row = (lane>>4)*4 + j
    if (wsel < 2) {
        short* __restrict__ outp = (wsel == 0) ? qb : kb;
        const float sc = (wsel == 0) ? 0.125f : 1.0f;   // fold softmax scale into q
        #pragma unroll
        for (int mf = 0; mf < 4; ++mf)
            #pragma unroll
            for (int nf = 0; nf < 2; ++nf) {
                int row = m0 + wm + mf*16 + g*4;
                int col = wn + nf*16 + c;
                #pragma unroll
                for (int j = 0; j < 4; ++j)
                    outp[(size_t)(row + j) * 64 + col] = f2bf(acc[mf][nf][j] * sc);
            }
    } else {
        #pragma unroll
        for (int mf = 0; mf < 4; ++mf)
            #pragma unroll
            for (int nf = 0; nf < 2; ++nf) {
                int row = m0 + wm + mf*16 + g*4;       // token index, 4 contiguous
                int h = wn + nf*16 + c;
                int bb = row >> 10, t = row & 1023;
                s16x4 sv = { f2bf(acc[mf][nf][0]), f2bf(acc[mf][nf][1]),
                             f2bf(acc[mf][nf][2]), f2bf(acc[mf][nf][3]) };
                *reinterpret_cast<s16x4*>(&vtb[(size_t)bb*65536 + (size_t)h*1024 + t]) = sv;
            }
    }
}

// ---------------- Kernel 2: causal flash attention ---------------------------
// Per block: one batch b, 64 q-rows (4 waves x 16). No LDS, no barriers.
// S^T = K.Q^T so softmax reduces over lane-local regs + shfl(16,32).
__global__ __launch_bounds__(256) void attn_fwd(
    const short* __restrict__ qb, const short* __restrict__ kb,
    const short* __restrict__ vtb, float* __restrict__ out)
{
    const int qt = blockIdx.x;
    const int b = blockIdx.y;
    const int tid = threadIdx.x;
    const int lane = tid & 63;
    const int w = tid >> 6;
    const int g = lane >> 4;
    const int c = lane & 15;
    const int q0 = qt * 64 + w * 16;
    const int qglob = q0 + c;

    const short* __restrict__ qB = qb + (size_t)b * 65536;
    const short* __restrict__ kB = kb + (size_t)b * 65536;
    const short* __restrict__ vB = vtb + (size_t)b * 65536;

    s16x8 qf[2];
    #pragma unroll
    for (int kk = 0; kk < 2; ++kk)
        qf[kk] = *reinterpret_cast<const s16x8*>(qB + (size_t)(q0 + c) * 64 + kk*32 + g*8);

    f32x4 oacc[4];
    #pragma unroll
    for (int i = 0; i < 4; ++i) oacc[i] = (f32x4)0.0f;
    float mrow = -1e30f, den = 0.0f;

    const int srcA = c + ((g & 1) << 5);    // P^T relayout source lanes
    const int srcB = srcA + 16;
    const bool hi = (g >> 1) != 0;

    for (int j = 0; j <= qt; ++j) {
        const int kv0 = j << 6;
        f32x4 sacc[4];
        #pragma unroll
        for (int mf = 0; mf < 4; ++mf) sacc[mf] = (f32x4)0.0f;
        #pragma unroll
        for (int mf = 0; mf < 4; ++mf)
            #pragma unroll
            for (int kk = 0; kk < 2; ++kk) {
                s16x8 kf = *reinterpret_cast<const s16x8*>(kB + (size_t)(kv0 + mf*16 + c) * 64 + kk*32 + g*8);
                sacc[mf] = __builtin_amdgcn_mfma_f32_16x16x32_bf16(kf, qf[kk], sacc[mf], 0, 0, 0);
            }
        if (j == qt) {                       // causal mask, diagonal tile only
            #pragma unroll
            for (int mf = 0; mf < 4; ++mf)
                #pragma unroll
                for (int jj = 0; jj < 4; ++jj) {
                    int kv = kv0 + mf*16 + g*4 + jj;
                    if (kv > qglob) sacc[mf][jj] = -1e30f;
                }
        }
        float mt = -1e30f;
        #pragma unroll
        for (int mf = 0; mf < 4; ++mf)
            #pragma unroll
            for (int jj = 0; jj < 4; ++jj) mt = fmaxf(mt, sacc[mf][jj]);
        mt = fmaxf(mt, __shfl_xor(mt, 16));
        mt = fmaxf(mt, __shfl_xor(mt, 32));
        const float mnew = fmaxf(mrow, mt);
        const float rescale = __expf(mrow - mnew);
        mrow = mnew;

        unsigned pp01[4], pp23[4];
        float psum = 0.0f;
        #pragma unroll
        for (int mf = 0; mf < 4; ++mf) {
            float p0 = __expf(sacc[mf][0] - mnew);
            float p1 = __expf(sacc[mf][1] - mnew);
            float p2 = __expf(sacc[mf][2] - mnew);
            float p3 = __expf(sacc[mf][3] - mnew);
            psum += (p0 + p1) + (p2 + p3);
            pp01[mf] = pack2(p0, p1);
            pp23[mf] = pack2(p2, p3);
        }
        psum += __shfl_xor(psum, 16);
        psum += __shfl_xor(psum, 32);
        den = den * rescale + psum;
        #pragma unroll
        for (int hf = 0; hf < 4; ++hf) oacc[hf] *= rescale;

        // P^T acc layout -> PV B-frag, pure in-register (verified lane map)
        s16x8 pf[2];
        #pragma unroll
        for (int kkv = 0; kkv < 2; ++kkv) {
            int w0a = __shfl((int)pp01[2*kkv],     srcA);
            int w0b = __shfl((int)pp01[2*kkv + 1], srcA);
            int w1a = __shfl((int)pp23[2*kkv],     srcA);
            int w1b = __shfl((int)pp23[2*kkv + 1], srcA);
            int w2a = __shfl((int)pp01[2*kkv],     srcB);
            int w2b = __shfl((int)pp01[2*kkv + 1], srcB);
            int w3a = __shfl((int)pp23[2*kkv],     srcB);
            int w3b = __shfl((int)pp23[2*kkv + 1], srcB);
            i32x4 wv = { hi ? w0b : w0a, hi ? w1b : w1a, hi ? w2b : w2a, hi ? w3b : w3a };
            pf[kkv] = __builtin_bit_cast(s16x8, wv);
        }
        #pragma unroll
        for (int hf = 0; hf < 4; ++hf)
            #pragma unroll
            for (int kkv = 0; kkv < 2; ++kkv) {
                s16x8 vf = *reinterpret_cast<const s16x8*>(vB + (size_t)(hf*16 + c) * 1024 + kv0 + kkv*32 + g*8);
                oacc[hf] = __builtin_amdgcn_mfma_f32_16x16x32_bf16(vf, pf[kkv], oacc[hf], 0, 0, 0);
            }
    }

    const float inv = 1.0f / den;
    #pragma unroll
    for (int hf = 0; hf < 4; ++hf) {
        f32x4 o = oacc[hf] * inv;
        *reinterpret_cast<f32x4*>(out + (size_t)b * 65536 + (size_t)(q0 + c) * 64 + hf*16 + g*4) = o;
    }
}

extern "C" void kernel_launch(void* const* d_in, const int* in_sizes, int n_in,
                              void* d_out, int out_size, void* d_ws, size_t ws_size,
                              hipStream_t stream)
{
    const float* x  = (const float*)d_in[0];
    // d_in[1] = freqs_cis (unused by the reference module)
    const float* Wq = (const float*)d_in[2];
    const float* Wk = (const float*)d_in[3];
    const float* Wv = (const float*)d_in[4];
    float* out = (float*)d_out;

    short* qb  = (short*)d_ws;                     // [32768][64] bf16 (pre-scaled)
    short* kb  = qb + (size_t)32768 * 64;          // [32768][64] bf16
    short* vtb = kb + (size_t)32768 * 64;          // [32][64][1024] bf16 (V^T)

    qkv_gemm<<<dim3(3, 256), 256, 0, stream>>>(x, Wq, Wk, Wv, qb, kb, vtb);
    attn_fwd<<<dim3(16, 32), 256, 0, stream>>>(qb, kb, vtb, out);
}

// Round 2
// 269.897 us; speedup vs baseline: 1.0380x; 1.0380x over previous
//
#include <hip/hip_runtime.h>
#include <hip/hip_bf16.h>

typedef __attribute__((ext_vector_type(4))) float f32x4;
typedef __attribute__((ext_vector_type(8))) short s16x8;
typedef __attribute__((ext_vector_type(4))) short s16x4;
typedef __attribute__((ext_vector_type(4))) int   i32x4;

static __device__ __forceinline__ unsigned short f2bf_bits(float f) {
    unsigned u = __builtin_bit_cast(unsigned, f);
    u += 0x7fffu + ((u >> 16) & 1u);   // RNE; no NaNs in this problem
    return (unsigned short)(u >> 16);
}
static __device__ __forceinline__ short f2bf(float f) { return (short)f2bf_bits(f); }
static __device__ __forceinline__ unsigned pack2(float a, float b) {
    return (unsigned)f2bf_bits(a) | ((unsigned)f2bf_bits(b) << 16);
}

// ---------- Kernel 0: W (3x[64,1024] f32) -> bf16 B-fragments -----------------
// wfrag frag id = (kt*2+kk)*12 + nf ; lane l holds W[nf*16+(l&15)][kt*64+kk*32+(l>>4)*8 ..+8]
__global__ __launch_bounds__(256) void wconv(
    const float* __restrict__ Wq, const float* __restrict__ Wk,
    const float* __restrict__ Wv, short* __restrict__ wfrag)
{
    int idx = blockIdx.x * 256 + threadIdx.x;        // 0..24575
    int lane = idx & 63;
    int rest = idx >> 6;                              // 0..383
    int nf = rest % 12;
    int kkkt = rest / 12;
    int kk = kkkt & 1, kt = kkkt >> 1;
    int n = nf * 16 + (lane & 15);                    // 0..191
    int col = kt * 64 + kk * 32 + (lane >> 4) * 8;
    const float* W = (n < 64) ? Wq : ((n < 128) ? Wk : Wv);
    const float* src = W + (size_t)(n & 63) * 1024 + col;
    s16x8 v;
    #pragma unroll
    for (int i = 0; i < 8; ++i) v[i] = f2bf(src[i]);
    *reinterpret_cast<s16x8*>(wfrag + (size_t)idx * 8) = v;
}

// ---------- Kernel 1: fused QKV projection -----------------------------------
// X [32768,1024] f32 read ONCE. 512 blocks x 64 rows. A in LDS (padded),
// B-frags direct from L2 (pre-fragmented bf16). Depth-2 X prefetch pipeline.
__global__ __launch_bounds__(256, 2) void qkv_gemm(
    const float* __restrict__ X, const short* __restrict__ wfrag,
    short* __restrict__ qb, short* __restrict__ kb, short* __restrict__ vtb)
{
    __shared__ short al[64][72];                     // 144B rows: conflict-free b128
    const int tid = threadIdx.x;
    const int lane = tid & 63;
    const int w = tid >> 6;                          // wave: cols [w*48, w*48+48)
    const int g = lane >> 4, c = lane & 15;
    const int m0 = blockIdx.x * 64;

    const float* xbase = X + (size_t)(m0 + (tid >> 4)) * 1024 + (tid & 15) * 4;

    f32x4 acc[4][3];
    #pragma unroll
    for (int i = 0; i < 4; ++i)
        #pragma unroll
        for (int jn = 0; jn < 3; ++jn) acc[i][jn] = (f32x4)0.0f;

    float4 rA[4], rB[4];
    #pragma unroll
    for (int it = 0; it < 4; ++it) {
        rA[it] = *reinterpret_cast<const float4*>(xbase + (size_t)it * 16384 + 0 * 64);
        rB[it] = *reinterpret_cast<const float4*>(xbase + (size_t)it * 16384 + 1 * 64);
    }

    #define STORE_LDS(R)                                                        \
        _Pragma("unroll")                                                       \
        for (int it = 0; it < 4; ++it) {                                        \
            s16x4 sv = { f2bf(R[it].x), f2bf(R[it].y), f2bf(R[it].z), f2bf(R[it].w) }; \
            *reinterpret_cast<s16x4*>(&al[it * 16 + (tid >> 4)][(tid & 15) * 4]) = sv; \
        }

    #define LOAD_X(R, KT)                                                       \
        _Pragma("unroll")                                                       \
        for (int it = 0; it < 4; ++it)                                          \
            R[it] = *reinterpret_cast<const float4*>(xbase + (size_t)it * 16384 + (KT) * 64);

    #define COMPUTE(KT)                                                         \
        {                                                                       \
            s16x8 af[4][2];                                                     \
            _Pragma("unroll")                                                   \
            for (int mf = 0; mf < 4; ++mf)                                      \
                _Pragma("unroll")                                               \
                for (int kk = 0; kk < 2; ++kk)                                  \
                    af[mf][kk] = *reinterpret_cast<const s16x8*>(&al[mf * 16 + c][kk * 32 + g * 8]); \
            _Pragma("unroll")                                                   \
            for (int kk = 0; kk < 2; ++kk) {                                    \
                s16x8 bf[3];                                                    \
                _Pragma("unroll")                                               \
                for (int nf = 0; nf < 3; ++nf)                                  \
                    bf[nf] = *reinterpret_cast<const s16x8*>(wfrag + (size_t)((((KT) * 2 + kk) * 12) + (w * 3 + nf)) * 512 + lane * 8); \
                _Pragma("unroll")                                               \
                for (int mf = 0; mf < 4; ++mf)                                  \
                    _Pragma("unroll")                                           \
                    for (int nf = 0; nf < 3; ++nf)                              \
                        acc[mf][nf] = __builtin_amdgcn_mfma_f32_16x16x32_bf16(af[mf][kk], bf[nf], acc[mf][nf], 0, 0, 0); \
            }                                                                   \
        }

    for (int kt = 0; kt < 16; kt += 2) {
        __syncthreads();
        STORE_LDS(rA);
        __syncthreads();
        if (kt + 2 < 16) LOAD_X(rA, kt + 2);
        COMPUTE(kt);
        __syncthreads();
        STORE_LDS(rB);
        __syncthreads();
        if (kt + 3 < 16) LOAD_X(rB, kt + 3);
        COMPUTE(kt + 1);
    }
    #undef STORE_LDS
    #undef LOAD_X
    #undef COMPUTE

    // D layout: out-token = m0 + mf*16 + g*4 + j ; out-col = w*48 + nf*16 + c
    #pragma unroll
    for (int mf = 0; mf < 4; ++mf)
        #pragma unroll
        for (int nf = 0; nf < 3; ++nf) {
            int gcol = w * 48 + nf * 16 + c;
            int row = m0 + mf * 16 + g * 4;
            if (gcol < 64) {
                #pragma unroll
                for (int j = 0; j < 4; ++j)
                    qb[(size_t)(row + j) * 64 + gcol] = f2bf(acc[mf][nf][j] * 0.125f);
            } else if (gcol < 128) {
                #pragma unroll
                for (int j = 0; j < 4; ++j)
                    kb[(size_t)(row + j) * 64 + (gcol - 64)] = f2bf(acc[mf][nf][j]);
            } else {
                int bb = row >> 10, t = row & 1023;
                s16x4 sv = { f2bf(acc[mf][nf][0]), f2bf(acc[mf][nf][1]),
                             f2bf(acc[mf][nf][2]), f2bf(acc[mf][nf][3]) };
                *reinterpret_cast<s16x4*>(&vtb[(size_t)bb * 65536 + (size_t)(gcol - 128) * 1024 + t]) = sv;
            }
        }
}

// ---------- Kernel 2: causal flash attention, split-KV -----------------------
// 1024 blocks (32 qb x 32 batch) x 256 thr. Wave w: qgroup = w&1 (16 rows),
// split s = w>>1 processes tiles j = s, s+2, ... <= jd. LDS pair-combine.
__global__ __launch_bounds__(256, 4) void attn_fwd(
    const short* __restrict__ qb, const short* __restrict__ kb,
    const short* __restrict__ vtb, float* __restrict__ out)
{
    const int bx = blockIdx.x;                 // 0..31 (32 q-rows each)
    const int b = blockIdx.y;
    const int tid = threadIdx.x;
    const int lane = tid & 63;
    const int w = tid >> 6;
    const int qg = w & 1, s = w >> 1;
    const int g = lane >> 4, c = lane & 15;
    const int q0 = bx * 32 + qg * 16;
    const int qglob = q0 + c;
    const int jd = bx >> 1;                    // diagonal 64-wide KV tile

    __shared__ float smO[2][64][17];
    __shared__ float smM[2][2][64];

    const short* __restrict__ qB = qb + (size_t)b * 65536;
    const short* __restrict__ kB = kb + (size_t)b * 65536;
    const short* __restrict__ vB = vtb + (size_t)b * 65536;

    s16x8 qf[2];
    #pragma unroll
    for (int kk = 0; kk < 2; ++kk)
        qf[kk] = *reinterpret_cast<const s16x8*>(qB + (size_t)(q0 + c) * 64 + kk * 32 + g * 8);

    f32x4 oacc[4];
    #pragma unroll
    for (int i = 0; i < 4; ++i) oacc[i] = (f32x4)0.0f;
    float mrow = -1e30f, den = 0.0f;

    const int srcA = c + ((g & 1) << 5);
    const int srcB = srcA + 16;
    const bool hi = (g >> 1) != 0;

    for (int j = s; j <= jd; j += 2) {
        const int kv0 = j << 6;
        f32x4 sacc[4];
        #pragma unroll
        for (int mf = 0; mf < 4; ++mf) sacc[mf] = (f32x4)0.0f;
        #pragma unroll
        for (int mf = 0; mf < 4; ++mf)
            #pragma unroll
            for (int kk = 0; kk < 2; ++kk) {
                s16x8 kf = *reinterpret_cast<const s16x8*>(kB + (size_t)(kv0 + mf * 16 + c) * 64 + kk * 32 + g * 8);
                sacc[mf] = __builtin_amdgcn_mfma_f32_16x16x32_bf16(kf, qf[kk], sacc[mf], 0, 0, 0);
            }
        if (j == jd) {
            #pragma unroll
            for (int mf = 0; mf < 4; ++mf)
                #pragma unroll
                for (int jj = 0; jj < 4; ++jj) {
                    int kv = kv0 + mf * 16 + g * 4 + jj;
                    if (kv > qglob) sacc[mf][jj] = -1e30f;
                }
        }
        float mt = -1e30f;
        #pragma unroll
        for (int mf = 0; mf < 4; ++mf)
            #pragma unroll
            for (int jj = 0; jj < 4; ++jj) mt = fmaxf(mt, sacc[mf][jj]);
        mt = fmaxf(mt, __shfl_xor(mt, 16));
        mt = fmaxf(mt, __shfl_xor(mt, 32));
        const float mnew = fmaxf(mrow, mt);
        const float rescale = __expf(mrow - mnew);
        mrow = mnew;

        unsigned pp01[4], pp23[4];
        float psum = 0.0f;
        #pragma unroll
        for (int mf = 0; mf < 4; ++mf) {
            float p0 = __expf(sacc[mf][0] - mnew);
            float p1 = __expf(sacc[mf][1] - mnew);
            float p2 = __expf(sacc[mf][2] - mnew);
            float p3 = __expf(sacc[mf][3] - mnew);
            psum += (p0 + p1) + (p2 + p3);
            pp01[mf] = pack2(p0, p1);
            pp23[mf] = pack2(p2, p3);
        }
        psum += __shfl_xor(psum, 16);
        psum += __shfl_xor(psum, 32);
        den = den * rescale + psum;
        #pragma unroll
        for (int hf = 0; hf < 4; ++hf) oacc[hf] *= rescale;

        s16x8 pf[2];
        #pragma unroll
        for (int kkv = 0; kkv < 2; ++kkv) {
            int w0a = __shfl((int)pp01[2 * kkv],     srcA);
            int w0b = __shfl((int)pp01[2 * kkv + 1], srcA);
            int w1a = __shfl((int)pp23[2 * kkv],     srcA);
            int w1b = __shfl((int)pp23[2 * kkv + 1], srcA);
            int w2a = __shfl((int)pp01[2 * kkv],     srcB);
            int w2b = __shfl((int)pp01[2 * kkv + 1], srcB);
            int w3a = __shfl((int)pp23[2 * kkv],     srcB);
            int w3b = __shfl((int)pp23[2 * kkv + 1], srcB);
            i32x4 wv = { hi ? w0b : w0a, hi ? w1b : w1a, hi ? w2b : w2a, hi ? w3b : w3a };
            pf[kkv] = __builtin_bit_cast(s16x8, wv);
        }
        #pragma unroll
        for (int hf = 0; hf < 4; ++hf)
            #pragma unroll
            for (int kkv = 0; kkv < 2; ++kkv) {
                s16x8 vf = *reinterpret_cast<const s16x8*>(vB + (size_t)(hf * 16 + c) * 1024 + kv0 + kkv * 32 + g * 8);
                oacc[hf] = __builtin_amdgcn_mfma_f32_16x16x32_bf16(vf, pf[kkv], oacc[hf], 0, 0, 0);
            }
    }

    // ---- split combine via LDS (split 1 -> split 0) ----
    if (s == 1) {
        #pragma unroll
        for (int hf = 0; hf < 4; ++hf)
            #pragma unroll
            for (int jj = 0; jj < 4; ++jj)
                smO[qg][lane][hf * 4 + jj] = oacc[hf][jj];
        smM[qg][0][lane] = mrow;
        smM[qg][1][lane] = den;
    }
    __syncthreads();
    if (s == 0) {
        float m1 = smM[qg][0][lane];
        float d1 = smM[qg][1][lane];
        float mn = fmaxf(mrow, m1);
        float r0 = __expf(mrow - mn);
        float r1 = __expf(m1 - mn);
        float inv = 1.0f / (den * r0 + d1 * r1);
        #pragma unroll
        for (int hf = 0; hf < 4; ++hf) {
            f32x4 o;
            #pragma unroll
            for (int jj = 0; jj < 4; ++jj)
                o[jj] = (oacc[hf][jj] * r0 + smO[qg][lane][hf * 4 + jj] * r1) * inv;
            *reinterpret_cast<f32x4*>(out + (size_t)b * 65536 + (size_t)(q0 + c) * 64 + hf * 16 + g * 4) = o;
        }
    }
}

extern "C" void kernel_launch(void* const* d_in, const int* in_sizes, int n_in,
                              void* d_out, int out_size, void* d_ws, size_t ws_size,
                              hipStream_t stream)
{
    const float* x  = (const float*)d_in[0];
    // d_in[1] = freqs_cis (unused by the reference module)
    const float* Wq = (const float*)d_in[2];
    const float* Wk = (const float*)d_in[3];
    const float* Wv = (const float*)d_in[4];
    float* out = (float*)d_out;

    short* qb    = (short*)d_ws;                    // [32768][64] bf16 (pre-scaled)
    short* kb    = qb + (size_t)32768 * 64;         // [32768][64] bf16
    short* vtb   = kb + (size_t)32768 * 64;         // [32][64][1024] bf16 (V^T)
    short* wfrag = vtb + (size_t)32768 * 64;        // 24576 x 16B B-fragments

    wconv<<<96, 256, 0, stream>>>(Wq, Wk, Wv, wfrag);
    qkv_gemm<<<512, 256, 0, stream>>>(x, wfrag, qb, kb, vtb);
    attn_fwd<<<dim3(32, 32), 256, 0, stream>>>(qb, kb, vtb, out);
}

// Round 3
// 257.836 us; speedup vs baseline: 1.0865x; 1.0468x over previous
//
#include <hip/hip_runtime.h>
#include <hip/hip_bf16.h>

typedef __attribute__((ext_vector_type(4))) float f32x4;
typedef __attribute__((ext_vector_type(8))) short s16x8;
typedef __attribute__((ext_vector_type(4))) short s16x4;
typedef __attribute__((ext_vector_type(4))) int   i32x4;

static __device__ __forceinline__ unsigned short f2bf_bits(float f) {
    unsigned u = __builtin_bit_cast(unsigned, f);
    u += 0x7fffu + ((u >> 16) & 1u);   // RNE; no NaNs in this problem
    return (unsigned short)(u >> 16);
}
static __device__ __forceinline__ short f2bf(float f) { return (short)f2bf_bits(f); }
static __device__ __forceinline__ unsigned pack2(float a, float b) {
    return (unsigned)f2bf_bits(a) | ((unsigned)f2bf_bits(b) << 16);
}

// ---------- Kernel 0: W (3x[64,1024] f32) -> bf16 B-fragments -----------------
// frag id = (kt*2+kk)*12 + nf ; lane l holds W[nf*16+(l&15)][kt*64+kk*32+(l>>4)*8 ..+8]
__global__ __launch_bounds__(256) void wconv(
    const float* __restrict__ Wq, const float* __restrict__ Wk,
    const float* __restrict__ Wv, short* __restrict__ wfrag)
{
    int idx = blockIdx.x * 256 + threadIdx.x;        // 0..24575
    int lane = idx & 63;
    int rest = idx >> 6;                              // 0..383
    int nf = rest % 12;
    int kkkt = rest / 12;
    int kk = kkkt & 1, kt = kkkt >> 1;
    int n = nf * 16 + (lane & 15);                    // 0..191
    int col = kt * 64 + kk * 32 + (lane >> 4) * 8;
    const float* W = (n < 64) ? Wq : ((n < 128) ? Wk : Wv);
    const float* src = W + (size_t)(n & 63) * 1024 + col;
    s16x8 v;
    #pragma unroll
    for (int i = 0; i < 8; ++i) v[i] = f2bf(src[i]);
    *reinterpret_cast<s16x8*>(wfrag + (size_t)idx * 8) = v;
}

// ---------- Kernel 1: fused QKV projection -----------------------------------
// X [32768,1024] f32 read ONCE. 1024 blocks x 32 rows (4 blocks/CU). A in LDS,
// B-frags direct from L2 (pre-fragmented bf16). Depth-2 X register prefetch.
__global__ __launch_bounds__(256, 4) void qkv_gemm(
    const float* __restrict__ X, const short* __restrict__ wfrag,
    short* __restrict__ qb, short* __restrict__ kb, short* __restrict__ vtb)
{
    __shared__ short al[32][72];                     // 144B rows: aligned b128, 2-way max
    const int tid = threadIdx.x;
    const int lane = tid & 63;
    const int w = tid >> 6;                          // wave: cols [w*48, w*48+48)
    const int g = lane >> 4, c = lane & 15;
    const int m0 = blockIdx.x * 32;

    const float* xbase = X + (size_t)(m0 + (tid >> 3)) * 1024 + (tid & 7) * 8;

    f32x4 acc[2][3];
    #pragma unroll
    for (int i = 0; i < 2; ++i)
        #pragma unroll
        for (int jn = 0; jn < 3; ++jn) acc[i][jn] = (f32x4)0.0f;

    float4 rA[2], rB[2];

    #define LOAD_X(R, KT)                                                       \
        { R[0] = *reinterpret_cast<const float4*>(xbase + (KT) * 64);           \
          R[1] = *reinterpret_cast<const float4*>(xbase + (KT) * 64 + 4); }

    #define STORE_LDS(R)                                                        \
        { s16x8 sv = { f2bf(R[0].x), f2bf(R[0].y), f2bf(R[0].z), f2bf(R[0].w), \
                       f2bf(R[1].x), f2bf(R[1].y), f2bf(R[1].z), f2bf(R[1].w) }; \
          *reinterpret_cast<s16x8*>(&al[tid >> 3][(tid & 7) * 8]) = sv; }

    #define COMPUTE(KT)                                                         \
        {                                                                       \
            s16x8 af[2][2];                                                     \
            _Pragma("unroll")                                                   \
            for (int mf = 0; mf < 2; ++mf)                                      \
                _Pragma("unroll")                                               \
                for (int kk = 0; kk < 2; ++kk)                                  \
                    af[mf][kk] = *reinterpret_cast<const s16x8*>(&al[mf * 16 + c][kk * 32 + g * 8]); \
            _Pragma("unroll")                                                   \
            for (int kk = 0; kk < 2; ++kk) {                                    \
                s16x8 bf[3];                                                    \
                _Pragma("unroll")                                               \
                for (int nf = 0; nf < 3; ++nf)                                  \
                    bf[nf] = *reinterpret_cast<const s16x8*>(wfrag + (size_t)((((KT) * 2 + kk) * 12) + (w * 3 + nf)) * 512 + lane * 8); \
                _Pragma("unroll")                                               \
                for (int mf = 0; mf < 2; ++mf)                                  \
                    _Pragma("unroll")                                           \
                    for (int nf = 0; nf < 3; ++nf)                              \
                        acc[mf][nf] = __builtin_amdgcn_mfma_f32_16x16x32_bf16(af[mf][kk], bf[nf], acc[mf][nf], 0, 0, 0); \
            }                                                                   \
        }

    LOAD_X(rA, 0);
    LOAD_X(rB, 1);
    for (int kt = 0; kt < 16; kt += 2) {
        __syncthreads();
        STORE_LDS(rA);
        __syncthreads();
        if (kt + 2 < 16) LOAD_X(rA, kt + 2);
        COMPUTE(kt);
        __syncthreads();
        STORE_LDS(rB);
        __syncthreads();
        if (kt + 3 < 16) LOAD_X(rB, kt + 3);
        COMPUTE(kt + 1);
    }
    #undef STORE_LDS
    #undef LOAD_X
    #undef COMPUTE

    // D layout: out-token = m0 + mf*16 + g*4 + j ; out-col = w*48 + nf*16 + c
    #pragma unroll
    for (int mf = 0; mf < 2; ++mf)
        #pragma unroll
        for (int nf = 0; nf < 3; ++nf) {
            int gcol = w * 48 + nf * 16 + c;
            int row = m0 + mf * 16 + g * 4;
            if (gcol < 64) {
                #pragma unroll
                for (int j = 0; j < 4; ++j)
                    qb[(size_t)(row + j) * 64 + gcol] = f2bf(acc[mf][nf][j] * 0.125f);
            } else if (gcol < 128) {
                #pragma unroll
                for (int j = 0; j < 4; ++j)
                    kb[(size_t)(row + j) * 64 + (gcol - 64)] = f2bf(acc[mf][nf][j]);
            } else {
                int bb = row >> 10, t = row & 1023;
                s16x4 sv = { f2bf(acc[mf][nf][0]), f2bf(acc[mf][nf][1]),
                             f2bf(acc[mf][nf][2]), f2bf(acc[mf][nf][3]) };
                *reinterpret_cast<s16x4*>(&vtb[(size_t)bb * 65536 + (size_t)(gcol - 128) * 1024 + t]) = sv;
            }
        }
}

// ---------- Kernel 2: causal flash attention, 4-way split-KV -----------------
// 2048 blocks x 256 thr. Block: 16 q-rows of one batch; wave s handles KV
// tiles j = s, s+4, ... <= jd; 4-way LDS merge. XCD-swizzled batch mapping.
__global__ __launch_bounds__(256, 4) void attn_fwd(
    const short* __restrict__ qb, const short* __restrict__ kb,
    const short* __restrict__ vtb, float* __restrict__ out)
{
    const int bid = blockIdx.x;
    const int xcd = bid & 7, seq = bid >> 3;
    const int b = xcd * 4 + (seq >> 6);        // 4 batches per XCD -> KV L2-resident
    const int bx = seq & 63;                   // 16-row q-tile index
    const int tid = threadIdx.x;
    const int lane = tid & 63;
    const int s = tid >> 6;                    // wave = KV split
    const int g = lane >> 4, c = lane & 15;
    const int q0 = bx * 16;
    const int qglob = q0 + c;
    const int jd = bx >> 2;                    // diagonal 64-wide KV tile

    __shared__ float smM[4][64], smD[4][64];
    __shared__ float smO[4][4][64][5];         // [src][hf][lane][jj], pad 5: no conflicts

    const short* __restrict__ qB = qb + (size_t)b * 65536;
    const short* __restrict__ kB = kb + (size_t)b * 65536;
    const short* __restrict__ vB = vtb + (size_t)b * 65536;

    s16x8 qf[2];
    #pragma unroll
    for (int kk = 0; kk < 2; ++kk)
        qf[kk] = *reinterpret_cast<const s16x8*>(qB + (size_t)(q0 + c) * 64 + kk * 32 + g * 8);

    f32x4 oacc[4];
    #pragma unroll
    for (int i = 0; i < 4; ++i) oacc[i] = (f32x4)0.0f;
    float mrow = -1e30f, den = 0.0f;

    const int srcA = c + ((g & 1) << 5);
    const int srcB = srcA + 16;
    const bool hi = (g >> 1) != 0;

    for (int j = s; j <= jd; j += 4) {
        const int kv0 = j << 6;
        f32x4 sacc[4];
        #pragma unroll
        for (int mf = 0; mf < 4; ++mf) sacc[mf] = (f32x4)0.0f;
        #pragma unroll
        for (int mf = 0; mf < 4; ++mf)
            #pragma unroll
            for (int kk = 0; kk < 2; ++kk) {
                s16x8 kf = *reinterpret_cast<const s16x8*>(kB + (size_t)(kv0 + mf * 16 + c) * 64 + kk * 32 + g * 8);
                sacc[mf] = __builtin_amdgcn_mfma_f32_16x16x32_bf16(kf, qf[kk], sacc[mf], 0, 0, 0);
            }
        if (j == jd) {                          // causal mask, diagonal tile only
            #pragma unroll
            for (int mf = 0; mf < 4; ++mf)
                #pragma unroll
                for (int jj = 0; jj < 4; ++jj) {
                    int kv = kv0 + mf * 16 + g * 4 + jj;
                    if (kv > qglob) sacc[mf][jj] = -1e30f;
                }
        }
        float mt = -1e30f;
        #pragma unroll
        for (int mf = 0; mf < 4; ++mf)
            #pragma unroll
            for (int jj = 0; jj < 4; ++jj) mt = fmaxf(mt, sacc[mf][jj]);
        mt = fmaxf(mt, __shfl_xor(mt, 16));
        mt = fmaxf(mt, __shfl_xor(mt, 32));
        const float mnew = fmaxf(mrow, mt);
        const float rescale = __expf(mrow - mnew);
        mrow = mnew;

        unsigned pp01[4], pp23[4];
        float psum = 0.0f;
        #pragma unroll
        for (int mf = 0; mf < 4; ++mf) {
            float p0 = __expf(sacc[mf][0] - mnew);
            float p1 = __expf(sacc[mf][1] - mnew);
            float p2 = __expf(sacc[mf][2] - mnew);
            float p3 = __expf(sacc[mf][3] - mnew);
            psum += (p0 + p1) + (p2 + p3);
            pp01[mf] = pack2(p0, p1);
            pp23[mf] = pack2(p2, p3);
        }
        psum += __shfl_xor(psum, 16);
        psum += __shfl_xor(psum, 32);
        den = den * rescale + psum;
        #pragma unroll
        for (int hf = 0; hf < 4; ++hf) oacc[hf] *= rescale;

        // P^T acc layout -> PV B-frag, pure in-register
        s16x8 pf[2];
        #pragma unroll
        for (int kkv = 0; kkv < 2; ++kkv) {
            int w0a = __shfl((int)pp01[2 * kkv],     srcA);
            int w0b = __shfl((int)pp01[2 * kkv + 1], srcA);
            int w1a = __shfl((int)pp23[2 * kkv],     srcA);
            int w1b = __shfl((int)pp23[2 * kkv + 1], srcA);
            int w2a = __shfl((int)pp01[2 * kkv],     srcB);
            int w2b = __shfl((int)pp01[2 * kkv + 1], srcB);
            int w3a = __shfl((int)pp23[2 * kkv],     srcB);
            int w3b = __shfl((int)pp23[2 * kkv + 1], srcB);
            i32x4 wv = { hi ? w0b : w0a, hi ? w1b : w1a, hi ? w2b : w2a, hi ? w3b : w3a };
            pf[kkv] = __builtin_bit_cast(s16x8, wv);
        }
        #pragma unroll
        for (int hf = 0; hf < 4; ++hf)
            #pragma unroll
            for (int kkv = 0; kkv < 2; ++kkv) {
                s16x8 vf = *reinterpret_cast<const s16x8*>(vB + (size_t)(hf * 16 + c) * 1024 + kv0 + kkv * 32 + g * 8);
                oacc[hf] = __builtin_amdgcn_mfma_f32_16x16x32_bf16(vf, pf[kkv], oacc[hf], 0, 0, 0);
            }
    }

    // ---- 4-way split combine via LDS; wave s owns output slice h in [s*16,s*16+16) ----
    #pragma unroll
    for (int hf = 0; hf < 4; ++hf)
        #pragma unroll
        for (int jj = 0; jj < 4; ++jj)
            smO[s][hf][lane][jj] = oacc[hf][jj];
    smM[s][lane] = mrow;
    smD[s][lane] = den;
    __syncthreads();

    float ms[4], rs[4];
    #pragma unroll
    for (int i = 0; i < 4; ++i) ms[i] = smM[i][lane];
    float mn = fmaxf(fmaxf(ms[0], ms[1]), fmaxf(ms[2], ms[3]));
    float dt = 0.0f;
    #pragma unroll
    for (int i = 0; i < 4; ++i) { rs[i] = __expf(ms[i] - mn); dt += rs[i] * smD[i][lane]; }
    const float inv = 1.0f / dt;
    f32x4 o;
    #pragma unroll
    for (int jj = 0; jj < 4; ++jj) {
        float a = 0.0f;
        #pragma unroll
        for (int i = 0; i < 4; ++i) a += rs[i] * smO[i][s][lane][jj];
        o[jj] = a * inv;
    }
    *reinterpret_cast<f32x4*>(out + (size_t)b * 65536 + (size_t)(q0 + c) * 64 + s * 16 + g * 4) = o;
}

extern "C" void kernel_launch(void* const* d_in, const int* in_sizes, int n_in,
                              void* d_out, int out_size, void* d_ws, size_t ws_size,
                              hipStream_t stream)
{
    const float* x  = (const float*)d_in[0];
    // d_in[1] = freqs_cis (unused by the reference module)
    const float* Wq = (const float*)d_in[2];
    const float* Wk = (const float*)d_in[3];
    const float* Wv = (const float*)d_in[4];
    float* out = (float*)d_out;

    short* qb    = (short*)d_ws;                    // [32768][64] bf16 (pre-scaled)
    short* kb    = qb + (size_t)32768 * 64;         // [32768][64] bf16
    short* vtb   = kb + (size_t)32768 * 64;         // [32][64][1024] bf16 (V^T)
    short* wfrag = vtb + (size_t)32768 * 64;        // 24576 x 16B B-fragments

    wconv<<<96, 256, 0, stream>>>(Wq, Wk, Wv, wfrag);
    qkv_gemm<<<1024, 256, 0, stream>>>(x, wfrag, qb, kb, vtb);
    attn_fwd<<<2048, 256, 0, stream>>>(qb, kb, vtb, out);
}